// Round 12
// baseline (3454.478 us; speedup 1.0000x reference)
//
#include <hip/hip_runtime.h>

// ---------------------------------------------------------------------------
// 2-layer GRU, T=512, B=64, I=H=512, fp32 in/out. Persistent cooperative
// kernel, 64 WGs x 512 thr, layers wavefront-pipelined (513 grid-steps).
// Round 12 (= r11 engine + serial-chain cuts):
//  - SPLIT BARRIER DOMAINS: L0 WGs poll only the 32 L0 flags (all their
//    deps are L0-produced; L1's out[] overwrite is provably behind). L1
//    polls all 64, but L0 free-runs ahead so its wait ~= own 32 peers.
//  - L0 x-slab PREFETCH: x-scratch is static; DMA next step's x right after
//    the flag store (overlaps poll). Post-poll DMA halves to 64 KB.
//  - part[] no longer aliases alds (LDS 152 KB) -> one less __syncthreads.
//  - u16 packed flags: 64 flags in 2 lines, 8 poll lanes.
//  - engine unchanged: W stationary bf16 hi+lo in VGPRs, A bf16-RNE staged
//    via global_load_lds, fresh-address rings, sc0 sc1 write-through, entry
//    acquire fence.
// ---------------------------------------------------------------------------

typedef float f32x4 __attribute__((ext_vector_type(4)));
typedef short s16x8 __attribute__((ext_vector_type(8)));
typedef unsigned u32x2 __attribute__((ext_vector_type(2)));
typedef unsigned u32x4 __attribute__((ext_vector_type(4)));

#define GB_T 512
#define NWG 64
#define NTHR 512
#define SLAB 32768  // ushorts per bf16 slab (64 KB)

// float-word offsets inside ws
#define OFF_FLAGS 0  // 64 u16 flags (128 B), padded region to 1024 floats
#define OFF_RING1 1024
#define OFF_RING2 (OFF_RING1 + 513 * (SLAB / 2))

__device__ __forceinline__ void st_coh_u16(unsigned short* p, unsigned v) {
  asm volatile("global_store_short %0, %1, off sc0 sc1" ::"v"(p), "v"(v)
               : "memory");
}
__device__ __forceinline__ void st_coh_u32(unsigned* p, unsigned v) {
  asm volatile("global_store_dword %0, %1, off sc0 sc1" ::"v"(p), "v"(v)
               : "memory");
}
__device__ __forceinline__ void st_coh_u32x2(unsigned* p, u32x2 v) {
  asm volatile("global_store_dwordx2 %0, %1, off sc0 sc1" ::"v"(p), "v"(v)
               : "memory");
}
__device__ __forceinline__ void st_coh_u32x4(unsigned* p, u32x4 v) {
  asm volatile("global_store_dwordx4 %0, %1, off sc0 sc1" ::"v"(p), "v"(v)
               : "memory");
}
#define LDC4U(dst, addr)                                  \
  asm volatile("global_load_dwordx4 %0, %1, off sc0 sc1" \
               : "=v"(dst)                                \
               : "v"(addr))

// async global->LDS DMA, 16 B per lane; LDS dest = uniform base + lane*16
__device__ __forceinline__ void dma16(const void* gsrc, void* ldst) {
  __builtin_amdgcn_global_load_lds(
      (const __attribute__((address_space(1))) unsigned*)gsrc,
      (__attribute__((address_space(3))) unsigned*)ldst, 16, 0, 0);
}

// Poll u16 flags: lanes c0..c1-1 each own one 16-B chunk (8 flags).
__device__ __forceinline__ void poll_flags(const unsigned* fbase, int c0,
                                           int c1, unsigned tgt) {
  const int lane = threadIdx.x & 63;
  const bool mine = (lane >= c0) && (lane < c1);
  const unsigned* fp = fbase + lane * 4;
  for (;;) {
    int ok = 1;
    if (mine) {
      u32x4 f;
      LDC4U(f, fp);
      asm volatile("s_waitcnt vmcnt(0)" ::: "memory");
      ok = ((f.x & 0xFFFFu) >= tgt) & ((f.x >> 16) >= tgt) &
           ((f.y & 0xFFFFu) >= tgt) & ((f.y >> 16) >= tgt) &
           ((f.z & 0xFFFFu) >= tgt) & ((f.z >> 16) >= tgt) &
           ((f.w & 0xFFFFu) >= tgt) & ((f.w >> 16) >= tgt);
    }
    if (__all(ok)) break;
    __builtin_amdgcn_s_sleep(1);
  }
}

__device__ __forceinline__ unsigned rne1(float f) {
  unsigned u = __float_as_uint(f);
  return (u + 0x7FFFu + ((u >> 16) & 1u)) >> 16;
}
__device__ __forceinline__ unsigned pack2(float a, float b) {
  return rne1(a) | (rne1(b) << 16);
}

// fp32 row-major [64][512] slab -> tiled bf16-RNE slab (SLAB ushorts)
__device__ __forceinline__ void convert_slab(const float* __restrict__ src,
                                             unsigned short* __restrict__ dst,
                                             int tid) {
  const int row = tid & 63;
  const int kg0 = tid >> 6;
#pragma unroll
  for (int i = 0; i < 8; ++i) {
    const int kg = kg0 + 8 * i;
    const float* s = src + row * 512 + kg * 8;
    f32x4 a = *(const f32x4*)s;
    f32x4 b = *(const f32x4*)(s + 4);
    u32x4 o;
    o.x = pack2(a.x, a.y);
    o.y = pack2(a.z, a.w);
    o.z = pack2(b.x, b.y);
    o.w = pack2(b.z, b.w);
    st_coh_u32x4((unsigned*)(dst + kg * 512 + row * 8), o);
  }
}

__global__ void gru_init(float* __restrict__ ws) {
  if (threadIdx.x < 32)
    st_coh_u32(((unsigned*)(ws + OFF_FLAGS)) + threadIdx.x, 0u);
}

__global__ __launch_bounds__(NTHR, 1) void gru_persist(
    const float* __restrict__ x, const float* __restrict__ h0,
    const float* __restrict__ w_ih, const float* __restrict__ w_hh,
    const float* __restrict__ b_ih, const float* __restrict__ b_hh,
    float* __restrict__ out, float* __restrict__ ws) {
  __shared__ unsigned short alds[2][SLAB];  // 128 KB A staging
  __shared__ float part[24 * 256];          // 24 KB C-tiles (separate!)

  const int tid = threadIdx.x;
  const int lane = tid & 63;
  const int wave = __builtin_amdgcn_readfirstlane(tid >> 6);
  const int wg = blockIdx.x;
  const int layer = wg >> 5;      // 0 or 1
  const int j0 = (wg & 31) << 4;  // 16 hidden cols per WG

  unsigned short* flags16 = (unsigned short*)(ws + OFF_FLAGS);
  const unsigned* fbase = (const unsigned*)(ws + OFF_FLAGS);
  unsigned short* ring1 = (unsigned short*)(ws + OFF_RING1);
  unsigned short* ring2 = (unsigned short*)(ws + OFF_RING2);

  // ---- prologue A: x -> tiled bf16 scratch in out[] slabs; h0 -> rings ----
  for (int i = 0; i < 8; ++i) {
    const int t = wg * 8 + i;
    convert_slab(x + (size_t)t * 32768,
                 (unsigned short*)(out + (size_t)t * 32768), tid);
  }
  if (wg == 0) convert_slab(h0, ring1, tid);
  if (wg == 1) convert_slab(h0 + 32768, ring2, tid);

  // ---- prologue B: stationary weights (bf16 hi+lo) in VGPRs --------------
  const int g = wave % 3;
  const int kh = wave / 3;
  s16x8 bhi[16], blo[16];
  if (wave < 6) {
    const float* Wb = (kh ? w_hh : w_ih) + (size_t)layer * 1536 * 512 +
                      (size_t)(g * 512 + j0 + (lane & 15)) * 512 +
                      ((lane >> 4) * 8);
#pragma unroll
    for (int k = 0; k < 16; ++k) {
      const float* p = Wb + k * 32;
      s16x8 vh, vl;
#pragma unroll
      for (int e = 0; e < 8; ++e) {
        float w = p[e];
        unsigned hb = __float_as_uint(w) & 0xFFFF0000u;
        float resid = w - __uint_as_float(hb);
        vh[e] = (short)(hb >> 16);
        vl[e] = (short)(__float_as_uint(resid) >> 16);
      }
      bhi[k] = vh;
      blo[k] = vl;
    }
  }

  // ---- prologue C: per-thread epilogue state in registers ----------------
  const int eb = tid >> 3;
  const int ejp = (tid & 7) * 2;
  float hprev0 = h0[((size_t)(layer * 64 + eb)) * 512 + j0 + ejp];
  float hprev1 = h0[((size_t)(layer * 64 + eb)) * 512 + j0 + ejp + 1];
  float bx0[3], bx1[3], bhh0[3], bhh1[3];
#pragma unroll
  for (int gg = 0; gg < 3; ++gg) {
    bx0[gg] = b_ih[layer * 1536 + gg * 512 + j0 + ejp];
    bx1[gg] = b_ih[layer * 1536 + gg * 512 + j0 + ejp + 1];
    bhh0[gg] = b_hh[layer * 1536 + gg * 512 + j0 + ejp];
    bhh1[gg] = b_hh[layer * 1536 + gg * 512 + j0 + ejp + 1];
  }

  // Drop stale cache lines (poison / prior replay) before cached DMA reads.
  __builtin_amdgcn_fence(__ATOMIC_ACQUIRE, "agent");

  // ---- prologue barrier (flag value 1, all 64 WGs) ----
  asm volatile("s_waitcnt vmcnt(0)" ::: "memory");
  __syncthreads();
  if (tid == 0) st_coh_u16(&flags16[wg], 1u);
  poll_flags(fbase, 0, 8, 1u);

  // L0: initial x-DMA for t=0 (x-scratch now globally visible).
  if (layer == 0) {
    const char* sx = (const char*)out;
#pragma unroll
    for (int i = 0; i < 8; ++i) {
      const int r = wave * 8 + i;
      dma16(sx + r * 1024 + lane * 16, (char*)&alds[0][0] + r * 1024);
    }
  }

  const int l15 = lane & 15, lg = lane >> 4;
  const int em = eb >> 4, erow = eb & 15;

  for (int s = 0; s <= GB_T; ++s) {
    const int t = layer ? s - 1 : s;
    const bool active = layer ? (s >= 1) : (s < GB_T);
    const unsigned tgt = (unsigned)(s + 1);

    // ---- entry poll (split domains) + DMA ----
    if (layer == 0) {
      poll_flags(fbase, 0, 4, tgt);  // own layer only
      if (active) {
        const char* src1 = (const char*)(ring1 + (size_t)t * SLAB);
#pragma unroll
        for (int i = 0; i < 8; ++i) {
          const int r = wave * 8 + i;
          dma16(src1 + r * 1024 + lane * 16, (char*)&alds[1][0] + r * 1024);
        }
      }
    } else {
      poll_flags(fbase, 0, 8, tgt);  // L0 flags pre-satisfied (free-running)
      if (active) {
        const char* src0 = (const char*)(ring1 + (size_t)(t + 1) * SLAB);
        const char* src1 = (const char*)(ring2 + (size_t)t * SLAB);
#pragma unroll
        for (int i = 0; i < 8; ++i) {
          const int r = wave * 8 + i;
          dma16(src0 + r * 1024 + lane * 16, (char*)&alds[0][0] + r * 1024);
          dma16(src1 + r * 1024 + lane * 16, (char*)&alds[1][0] + r * 1024);
        }
      }
    }
    asm volatile("s_waitcnt vmcnt(0)" ::: "memory");
    __syncthreads();  // A: LDS slabs ready

    // ---- MFMA phase + C-tile write (part[] separate -> no mid sync) ----
    if (active && wave < 6) {
      f32x4 acc[4];
#pragma unroll
      for (int m = 0; m < 4; ++m) acc[m] = (f32x4)(0.f);
      const char* base = (const char*)&alds[kh][0] + lg * 1024 + l15 * 16;
#pragma unroll
      for (int k = 0; k < 16; ++k) {
        const s16x8 bh = bhi[k], bl = blo[k];
#pragma unroll
        for (int m = 0; m < 4; ++m) {
          const s16x8 ah = *(const s16x8*)(base + k * 4096 + m * 256);
          acc[m] =
              __builtin_amdgcn_mfma_f32_16x16x32_bf16(ah, bh, acc[m], 0, 0, 0);
          acc[m] =
              __builtin_amdgcn_mfma_f32_16x16x32_bf16(ah, bl, acc[m], 0, 0, 0);
        }
      }
      const int tbase = ((g * 2 + kh) * 4) * 256;
#pragma unroll
      for (int m = 0; m < 4; ++m)
#pragma unroll
        for (int r2 = 0; r2 < 4; ++r2)
          part[tbase + m * 256 + (lg * 4 + r2) * 16 + l15] = acc[m][r2];
    }
    __syncthreads();  // B: part[] complete, alds reads done

    // ---- epilogue: gates + h update + stores ----
    if (active) {
      float X0[3], H0[3], X1[3], H1[3];
#pragma unroll
      for (int gg = 0; gg < 3; ++gg) {
        X0[gg] =
            part[((gg * 2 + 0) * 4 + em) * 256 + erow * 16 + ejp] + bx0[gg];
        H0[gg] =
            part[((gg * 2 + 1) * 4 + em) * 256 + erow * 16 + ejp] + bhh0[gg];
        X1[gg] = part[((gg * 2 + 0) * 4 + em) * 256 + erow * 16 + ejp + 1] +
                 bx1[gg];
        H1[gg] = part[((gg * 2 + 1) * 4 + em) * 256 + erow * 16 + ejp + 1] +
                 bhh1[gg];
      }
      const float r0 = 1.f / (1.f + __expf(-(X0[0] + H0[0])));
      const float z0 = 1.f / (1.f + __expf(-(X0[1] + H0[1])));
      const float a0 = X0[2] + r0 * H0[2];
      const float n0 = 1.f - 2.f / (1.f + __expf(2.f * a0));
      const float hn0 = (1.f - z0) * n0 + z0 * hprev0;
      const float r1 = 1.f / (1.f + __expf(-(X1[0] + H1[0])));
      const float z1 = 1.f / (1.f + __expf(-(X1[1] + H1[1])));
      const float a1 = X1[2] + r1 * H1[2];
      const float n1 = 1.f - 2.f / (1.f + __expf(2.f * a1));
      const float hn1 = (1.f - z1) * n1 + z1 * hprev1;
      hprev0 = hn0;
      hprev1 = hn1;
      const int j = j0 + ejp;
      unsigned short* rdst = (layer ? ring2 : ring1) + (size_t)(t + 1) * SLAB +
                             (j >> 3) * 512 + eb * 8 + (j & 7);
      st_coh_u32((unsigned*)rdst, pack2(hn0, hn1));
      if (layer) {
        u32x2 fo;
        fo.x = __float_as_uint(hn0);
        fo.y = __float_as_uint(hn1);
        st_coh_u32x2((unsigned*)(out + (size_t)t * 32768 + eb * 512 + j), fo);
      }
    }
    asm volatile("s_waitcnt vmcnt(0)" ::: "memory");
    __syncthreads();  // C: all stores drained
    if (tid == 0) st_coh_u16(&flags16[wg], (unsigned)(s + 2));

    // L0: prefetch next x slab into alds[0]; overlaps the next poll. The
    // per-wave vmcnt(0) before syncA covers completion.
    if (layer == 0 && s + 1 < GB_T) {
      const char* sx = (const char*)(out + (size_t)(s + 1) * 32768);
#pragma unroll
      for (int i = 0; i < 8; ++i) {
        const int r = wave * 8 + i;
        dma16(sx + r * 1024 + lane * 16, (char*)&alds[0][0] + r * 1024);
      }
    }
  }
  asm volatile("s_waitcnt vmcnt(0)" ::: "memory");  // drain final stores
}

extern "C" void kernel_launch(void* const* d_in, const int* in_sizes, int n_in,
                              void* d_out, int out_size, void* d_ws,
                              size_t ws_size, hipStream_t stream) {
  const float* x = (const float*)d_in[0];
  const float* h0 = (const float*)d_in[1];
  const float* w_ih = (const float*)d_in[2];
  const float* w_hh = (const float*)d_in[3];
  const float* b_ih = (const float*)d_in[4];
  const float* b_hh = (const float*)d_in[5];
  float* out = (float*)d_out;
  float* ws = (float*)d_ws;

  gru_init<<<1, 64, 0, stream>>>(ws);

  void* args[] = {(void*)&x,    (void*)&h0,   (void*)&w_ih, (void*)&w_hh,
                  (void*)&b_ih, (void*)&b_hh, (void*)&out,  (void*)&ws};
  (void)hipLaunchCooperativeKernel((const void*)gru_persist, dim3(NWG),
                                   dim3(NTHR), args, 0, stream);
}